// Round 8
// baseline (198.814 us; speedup 1.0000x reference)
//
#include <hip/hip_runtime.h>

// Problem constants (match reference)
#define B_ 4
#define N_ 16384
#define M_ 128
#define C_ 128
#define S_ 512
#define ROW_ 131           // 3 + C floats per pooled row
#define NCHUNK_ 256        // 64-point chunks per box (N_/64)
#define KBOX_ 4            // boxes per wave in mask kernel

typedef float f4_t __attribute__((ext_vector_type(4)));

// ---------------------------------------------------------------------------
// Phase A: per-(box, chunk) in-box bitmask via wave ballot. (unchanged, R7)
// ---------------------------------------------------------------------------
__global__ __launch_bounds__(256) void mask_kernel(
    const float* __restrict__ points,        // (B, N, 3)
    const float* __restrict__ boxes,         // (B*M, 7)
    unsigned long long* __restrict__ masks)  // (B*M, NCHUNK_)
{
    const int gwave = blockIdx.x * 4 + (threadIdx.x >> 6);
    const int lane  = threadIdx.x & 63;
    const int grp   = gwave >> 4;            // box-group [0, B*M/KBOX_)
    const int seg   = gwave & 15;            // 16 chunks per segment
    const int bm0   = grp * KBOX_;
    const int b     = bm0 >> 7;              // batch (shared by the 4 boxes)

    const float* pb = points + (size_t)b * N_ * 3;
    float px[16], py[16], pz[16];
    #pragma unroll
    for (int k = 0; k < 16; ++k) {
        const int i = (seg * 16 + k) * 64 + lane;
        px[k] = pb[i*3+0]; py[k] = pb[i*3+1]; pz[k] = pb[i*3+2];
    }

    for (int kb = 0; kb < KBOX_; ++kb) {
        const int bm = bm0 + kb;
        const float* bx = boxes + bm * 7;
        const float cx = bx[0], cy = bx[1], czb = bx[2];
        const float dx = bx[3], dy = bx[4], dzv = bx[5], rz = bx[6];
        // fp32 reference semantics: no FMA contraction; trig via double->fp32
        const float cz   = __fadd_rn(czb, __fmul_rn(0.5f, dzv));
        const float cosa = (float)cos(-(double)rz);
        const float sina = (float)sin(-(double)rz);
        const float hdx = 0.5f * dx, hdy = 0.5f * dy, hdz = 0.5f * dzv;

        #pragma unroll
        for (int k = 0; k < 16; ++k) {
            const float sx = __fsub_rn(px[k], cx);
            const float sy = __fsub_rn(py[k], cy);
            const float lx = __fsub_rn(__fmul_rn(sx, cosa), __fmul_rn(sy, sina));
            const float ly = __fadd_rn(__fmul_rn(sx, sina), __fmul_rn(sy, cosa));
            const bool pred = (fabsf(__fsub_rn(pz[k], cz)) <= hdz) &&
                              (lx > -hdx) && (lx < hdx) &&
                              (ly > -hdy) && (ly < hdy);
            const unsigned long long m = __ballot(pred);
            if (lane == 0) masks[(size_t)bm * NCHUNK_ + seg * 16 + k] = m;
        }
    }
}

// ---------------------------------------------------------------------------
// R16: stateless light-block pool. Evidence ledger: 9 stream-side theories
// nulled; all heavyweight one-block-per-box variants give pool ~75-80 us
// (1.8 TB/s) with FETCH tiny, WRITE exact, VALU idle, conflicts nil.
// Last untested invariant: phase-synced heavyweight blocks. This variant is
// fill-shaped: 4 light blocks per box (grid 2048, 256 T, 8.2 KB LDS ->
// 8 blocks/CU), no srow staging, no heavy barrier before the stream.
// Per row: uniform s_idx[s%cnt] broadcast read -> lane-coalesced 256B feats
// row loads (L2/L3-hot re-reads, 2-deep chain vs R10's 4-deep) -> 3 dword
// stores. Prologue (scan+expand, proven R7 logic) is duplicated 4x but
// costs ~2 us (R8's lesson was about duplicating the HEAVY prologue).
// ---------------------------------------------------------------------------
__global__ __launch_bounds__(256, 4) void pool_kernel(
    const float* __restrict__ points,        // (B, N, 3)
    const float* __restrict__ feats,         // (B, N, C)
    const unsigned long long* __restrict__ masks,
    float* __restrict__ out,                 // (B, M, S, 131)
    float* __restrict__ flags_out)           // (B*M,)
{
    const int blk  = blockIdx.x;
    const int bm   = blk >> 2;               // box
    const int q    = blk & 3;                // quarter of the box's rows
    const int b    = bm >> 7;
    const int tid  = threadIdx.x;
    const int w    = tid >> 6;
    const int lane = tid & 63;

    __shared__ int   s_wsum[4];
    __shared__ int   s_idx[S_];
    __shared__ float s_xyz[S_ * 3];          // xyz per unique row (6 KB)

    // --- mask word + scan (proven R7/R11 logic) ---
    const unsigned long long m0 = masks[(size_t)bm * NCHUNK_ + tid];
    const int c = __popcll(m0);
    int incl = c;
    #pragma unroll
    for (int d = 1; d < 64; d <<= 1) {
        const int t = __shfl_up(incl, d, 64);
        if (lane >= d) incl += t;
    }
    if (lane == 63) s_wsum[w] = incl;
    __syncthreads();
    const int w0 = s_wsum[0], w1 = s_wsum[1], w2 = s_wsum[2], w3 = s_wsum[3];
    const int woff  = (w > 0 ? w0 : 0) + (w > 1 ? w1 : 0) + (w > 2 ? w2 : 0);
    const int total = w0 + w1 + w2 + w3;
    int pos = incl - c + woff;               // exclusive prefix (ordered)

    // --- expand ordered in-box indices ---
    if (c > 0 && pos < S_) {
        unsigned long long m = m0;
        while (m && pos < S_) {
            const int bit = __ffsll((unsigned long long)m) - 1;
            m &= m - 1;
            s_idx[pos++] = tid * 64 + bit;
        }
    }
    __syncthreads();                         // s_idx ready

    const int cnt_eff = total < S_ ? total : S_;
    const int denom   = cnt_eff > 0 ? cnt_eff : 1;

    float* ob = out + (size_t)bm * (S_ * ROW_);

    if (total == 0) {
        // empty box: 4 blocks each zero 128 rows = 16768 dwords
        for (int t = tid; t < 128 * ROW_; t += 256)
            ob[q * (128 * ROW_) + t] = 0.0f;
        if (q == 0 && tid == 0) flags_out[bm] = 1.0f;
        return;
    }

    // --- xyz cache for referenced rows (<=2 iters of 256 threads) ---
    for (int t = tid; t < cnt_eff; t += 256) {
        const size_t pbase = ((size_t)b * N_ + (unsigned)s_idx[t]) * 3;
        s_xyz[t*3+0] = points[pbase+0];
        s_xyz[t*3+1] = points[pbase+1];
        s_xyz[t*3+2] = points[pbase+2];
    }
    __syncthreads();                         // s_xyz ready

    // --- stream 128 rows: wave w owns rows q*128 + [w*32, w*32+32) ---------
    const float* fb = feats + (size_t)b * N_ * C_;
    const int s0 = q * 128 + w * 32;
    #pragma unroll 4
    for (int k = 0; k < 32; ++k) {
        const int s = s0 + k;
        const int j = (int)((unsigned)s % (unsigned)denom);  // uniform
        const int idx = s_idx[j];            // uniform LDS broadcast
        const float* fr = fb + (size_t)(unsigned)idx * C_;
        // cols: lane -> [0,63], 64+lane -> [64,127], 128+lane(<3) -> [128,130]
        const float a  = (lane < 3) ? s_xyz[j*3 + lane] : fr[lane - 3];
        const float d2 = fr[61 + lane];
        const float d3 = (lane < 3) ? fr[125 + lane] : 0.0f;
        float* orow = ob + s * ROW_;
        orow[lane]      = a;                 // 256B coalesced dword stores
        orow[64 + lane] = d2;
        if (lane < 3) orow[128 + lane] = d3;
    }
    if (q == 0 && tid == 0) flags_out[bm] = 0.0f;
}

extern "C" void kernel_launch(void* const* d_in, const int* in_sizes, int n_in,
                              void* d_out, int out_size, void* d_ws, size_t ws_size,
                              hipStream_t stream) {
    const float* points = (const float*)d_in[0];   // (B, N, 3)
    const float* feats  = (const float*)d_in[1];   // (B, N, C)
    const float* boxes  = (const float*)d_in[2];   // (B, M, 7)
    float* out = (float*)d_out;

    // Workspace: masks (1 MB)
    unsigned long long* masks = (unsigned long long*)d_ws;

    float* flags = out + (size_t)B_ * M_ * S_ * ROW_;

    // Phase A: (512/KBOX_) box-groups x 16 segments = 2048 waves = 512 blocks
    mask_kernel<<<B_ * M_ * 16 / 4 / KBOX_, 256, 0, stream>>>(
        points, boxes, masks);
    // Resolve + pool: 4 light blocks per box, stateless fill-shaped stream
    pool_kernel<<<B_ * M_ * 4, 256, 0, stream>>>(points, feats, masks, out, flags);
}

// Round 9
// 170.814 us; speedup vs baseline: 1.1639x; 1.1639x over previous
//
#include <hip/hip_runtime.h>

// Problem constants (match reference)
#define B_ 4
#define N_ 16384
#define M_ 128
#define C_ 128
#define S_ 512
#define ROW_ 131           // 3 + C floats per pooled row
#define NCHUNK_ 256        // 64-point chunks per box (N_/64)
#define TILE_ 128          // unique rows staged in LDS per box
#define LSTR_ 136          // swizzled LDS row stride (floats)
#define KBOX_ 4            // boxes per wave in mask kernel

// R17 = R11 verbatim (measured 171.6 us, session best). Final state.
// Session ledger: NT->plain stores -11 us (R9); batched 8-deep stores -2.4
// (R11); all other stream/structure variants null or regressions (R10 +8,
// R12 +37, R13 +59, R14 +5, R15 +4, R16 +27). Floor accounting:
// fill 85 (harness, at HBM roofline) + restores/gaps ~38 (harness) +
// mask ~5 (issue floor) + pool ~45 vs 28 roofline. The ~15 us pool excess
// is counter-unattributable (WRITE exact, FETCH tiny, VALU 15%, conflicts
// nil, occupancy/TLP/store-shape swept) -> dependent-source store-stream
// cap; no remaining HIP-level lever identified.

typedef float f4_t __attribute__((ext_vector_type(4)));

// Swizzled LDS address: for a fixed element-within-float4 slot, consecutive
// lanes (col += 4) land on consecutive banks -> conflict-free ds_read_b32.
// Injective for col in [0,131): (col&3)*34 + (col>>2) <= 3*34+32 = 134 < 136.
__device__ __forceinline__ int swz(int j, int col) {
    return j * LSTR_ + (col & 3) * 34 + (col >> 2);
}

// ---------------------------------------------------------------------------
// Phase A: per-(box, chunk) in-box bitmask via wave ballot. (unchanged, R7)
// ---------------------------------------------------------------------------
__global__ __launch_bounds__(256) void mask_kernel(
    const float* __restrict__ points,        // (B, N, 3)
    const float* __restrict__ boxes,         // (B*M, 7)
    unsigned long long* __restrict__ masks)  // (B*M, NCHUNK_)
{
    const int gwave = blockIdx.x * 4 + (threadIdx.x >> 6);
    const int lane  = threadIdx.x & 63;
    const int grp   = gwave >> 4;            // box-group [0, B*M/KBOX_)
    const int seg   = gwave & 15;            // 16 chunks per segment
    const int bm0   = grp * KBOX_;
    const int b     = bm0 >> 7;              // batch (shared by the 4 boxes)

    const float* pb = points + (size_t)b * N_ * 3;
    float px[16], py[16], pz[16];
    #pragma unroll
    for (int k = 0; k < 16; ++k) {
        const int i = (seg * 16 + k) * 64 + lane;
        px[k] = pb[i*3+0]; py[k] = pb[i*3+1]; pz[k] = pb[i*3+2];
    }

    for (int kb = 0; kb < KBOX_; ++kb) {
        const int bm = bm0 + kb;
        const float* bx = boxes + bm * 7;
        const float cx = bx[0], cy = bx[1], czb = bx[2];
        const float dx = bx[3], dy = bx[4], dzv = bx[5], rz = bx[6];
        // fp32 reference semantics: no FMA contraction; trig via double->fp32
        const float cz   = __fadd_rn(czb, __fmul_rn(0.5f, dzv));
        const float cosa = (float)cos(-(double)rz);
        const float sina = (float)sin(-(double)rz);
        const float hdx = 0.5f * dx, hdy = 0.5f * dy, hdz = 0.5f * dzv;

        #pragma unroll
        for (int k = 0; k < 16; ++k) {
            const float sx = __fsub_rn(px[k], cx);
            const float sy = __fsub_rn(py[k], cy);
            const float lx = __fsub_rn(__fmul_rn(sx, cosa), __fmul_rn(sy, sina));
            const float ly = __fadd_rn(__fmul_rn(sx, sina), __fmul_rn(sy, cosa));
            const bool pred = (fabsf(__fsub_rn(pz[k], cz)) <= hdz) &&
                              (lx > -hdx) && (lx < hdx) &&
                              (ly > -hdy) && (ly < hdy);
            const unsigned long long m = __ballot(pred);
            if (lane == 0) masks[(size_t)bm * NCHUNK_ + seg * 16 + k] = m;
        }
    }
}

// ---------------------------------------------------------------------------
// Resolve + pool — R11 structure (LDS srow staging + 8-deep batched stores).
// ---------------------------------------------------------------------------
__global__ __launch_bounds__(512, 4) void pool_kernel(
    const float* __restrict__ points,        // (B, N, 3)
    const float* __restrict__ feats,         // (B, N, C)
    const unsigned long long* __restrict__ masks,
    float* __restrict__ out,                 // (B, M, S, 131)
    float* __restrict__ flags_out)           // (B*M,)
{
    const int bm   = blockIdx.x;
    const int b    = bm >> 7;
    const int tid  = threadIdx.x;
    const int w    = tid >> 6;
    const int lane = tid & 63;

    __shared__ int   s_wsum[4];
    __shared__ int   s_idx[S_];
    __shared__ int   jtab[S_ + 1];           // +1: streaming reads jtab[s0+1]
    __shared__ float srow[TILE_ * LSTR_];

    // --- mask words + scan: first 4 waves (256 words); others wait ---
    unsigned long long m0 = 0;
    int c = 0, Ppart = 0;
    if (tid < 256) {
        m0 = masks[(size_t)bm * NCHUNK_ + tid];
        c  = __popcll(m0);
        int incl = c;
        #pragma unroll
        for (int d = 1; d < 64; d <<= 1) {
            const int t = __shfl_up(incl, d, 64);
            if (lane >= d) incl += t;
        }
        if (lane == 63) s_wsum[w] = incl;
        Ppart = incl - c;                    // exclusive prefix within wave
    }
    __syncthreads();
    const int w0 = s_wsum[0], w1 = s_wsum[1], w2 = s_wsum[2], w3 = s_wsum[3];
    const int total = w0 + w1 + w2 + w3;

    // --- expand ordered in-box indices (mask already in register) ---
    if (tid < 256 && c > 0) {
        const int woff = (w > 0 ? w0 : 0) + (w > 1 ? w1 : 0) + (w > 2 ? w2 : 0);
        int pos = Ppart + woff;
        if (pos < S_) {
            unsigned long long m = m0;
            while (m && pos < S_) {
                const int bit = __ffsll((unsigned long long)m) - 1;
                m &= m - 1;
                s_idx[pos++] = tid * 64 + bit;
            }
        }
    }

    // --- wrap-around table (independent of s_idx) ---
    const int cnt_eff = total < S_ ? total : S_;
    const int denom   = cnt_eff > 0 ? cnt_eff : 1;
    for (int s = tid; s <= S_; s += 512)
        jtab[s] = (s < S_) ? (int)((unsigned)s % (unsigned)denom) : 0;
    __syncthreads();                         // s_idx + jtab ready

    // --- stage unique rows into swizzled LDS ---
    const int T = cnt_eff < TILE_ ? cnt_eff : TILE_;
    if (total == 0) {
        if (tid < LSTR_) srow[tid] = 0.0f;   // row 0 zeros (j is always 0)
    } else {
        const int nf4 = T * 32;              // 32 float4s of features per row
        for (int t = tid; t < nf4; t += 512) {
            const int u = t >> 5, q = t & 31;
            const size_t pbase = (size_t)b * N_ + (unsigned)s_idx[u];
            const f4_t v = *(const f4_t*)(feats + pbase * C_ + q * 4);
            #pragma unroll
            for (int jj = 0; jj < 4; ++jj)
                srow[swz(u, 3 + 4 * q + jj)] = v[jj];   // <=2-way: free
        }
        for (int t = tid; t < T * 3; t += 512) {
            const int u = t / 3, k = t - u * 3;
            const size_t pbase = (size_t)b * N_ + (unsigned)s_idx[u];
            srow[swz(u, k)] = points[pbase * 3 + k];
        }
    }
    __syncthreads();

    // --- stream output: 16768 float4s = 32 full 512-strides + 384 tail ---
    float* ob = out + (size_t)bm * (S_ * ROW_);
    if (cnt_eff <= TILE_) {
        // block-uniform fast path: every referenced row is staged
        #pragma unroll 1
        for (int bt = 0; bt < 4; ++bt) {
            f4_t v[8];
            #pragma unroll
            for (int u = 0; u < 8; ++u) {
                const int e = 4 * (tid + (bt * 8 + u) * 512);
                const unsigned s0 = (unsigned)e / (unsigned)ROW_;  // magic-mul
                const int col0 = e - (int)s0 * ROW_;
                const int ja = jtab[s0], jb = jtab[s0 + 1];
                #pragma unroll
                for (int jj = 0; jj < 4; ++jj) {
                    int col = col0 + jj;
                    const bool cross = col >= ROW_;
                    col = cross ? col - ROW_ : col;
                    const int j = cross ? jb : ja;
                    v[u][jj] = srow[swz(j, col)];   // stride-1 banks: no conflict
                }
            }
            #pragma unroll
            for (int u = 0; u < 8; ++u) {
                const int e = 4 * (tid + (bt * 8 + u) * 512);
                *(f4_t*)(ob + e) = v[u];     // 8 back-to-back stores in flight
            }
        }
        if (tid < 384) {                     // tail: f = tid + 16384
            const int e = 4 * (tid + 16384);
            const unsigned s0 = (unsigned)e / (unsigned)ROW_;
            const int col0 = e - (int)s0 * ROW_;
            const int ja = jtab[s0], jb = jtab[s0 + 1];
            f4_t v;
            #pragma unroll
            for (int jj = 0; jj < 4; ++jj) {
                int col = col0 + jj;
                const bool cross = col >= ROW_;
                col = cross ? col - ROW_ : col;
                const int j = cross ? jb : ja;
                v[jj] = srow[swz(j, col)];
            }
            *(f4_t*)(ob + e) = v;
        }
    } else {
        // rare path: some rows not staged -> per-element fallback to global
        for (int f = tid; f < (S_ * ROW_) / 4; f += 512) {
            const int e = 4 * f;
            const unsigned s0 = (unsigned)e / (unsigned)ROW_;
            const int col0 = e - (int)s0 * ROW_;
            f4_t v;
            #pragma unroll
            for (int jj = 0; jj < 4; ++jj) {
                int col = col0 + jj;
                unsigned s = s0;
                if (col >= ROW_) { col -= ROW_; ++s; }
                const int j = jtab[s];
                float val;
                if (j < TILE_) {
                    val = srow[swz(j, col)];
                } else {
                    const size_t pbase = (size_t)b * N_ + (unsigned)s_idx[j];
                    val = (col < 3) ? points[pbase * 3 + col]
                                    : feats[pbase * C_ + (col - 3)];
                }
                v[jj] = val;
            }
            *(f4_t*)(ob + e) = v;
        }
    }
    if (tid == 0) flags_out[bm] = (total == 0) ? 1.0f : 0.0f;
}

extern "C" void kernel_launch(void* const* d_in, const int* in_sizes, int n_in,
                              void* d_out, int out_size, void* d_ws, size_t ws_size,
                              hipStream_t stream) {
    const float* points = (const float*)d_in[0];   // (B, N, 3)
    const float* feats  = (const float*)d_in[1];   // (B, N, C)
    const float* boxes  = (const float*)d_in[2];   // (B, M, 7)
    float* out = (float*)d_out;

    // Workspace: masks (1 MB)
    unsigned long long* masks = (unsigned long long*)d_ws;

    float* flags = out + (size_t)B_ * M_ * S_ * ROW_;

    // Phase A: (512/KBOX_) box-groups x 16 segments = 2048 waves = 512 blocks
    mask_kernel<<<B_ * M_ * 16 / 4 / KBOX_, 256, 0, stream>>>(
        points, boxes, masks);
    // Resolve + pool: one 512-thread block per box
    pool_kernel<<<B_ * M_, 512, 0, stream>>>(points, feats, masks, out, flags);
}